// Round 9
// baseline (607.704 us; speedup 1.0000x reference)
//
#include <hip/hip_runtime.h>
#include <hip/hip_bf16.h>
#include <stdint.h>

#define B_ 128
#define T_ 255
#define N_ 256
#define H_ 256

// k4 k-QUARTER split (round 9): tid = kq*256 + n'. Thread owns the 4 GATE
// columns of unit n' (n', n'+256, n'+512, n'+768) over k-pairs
// [kq*32, kq*32+32). 24 pairs/col in registers (96 regs, the proven budget),
// 8 pairs/col in LDS (8 planes x 1024 x uint4 = 128 KB). vs round-5: h-reads
// halve (8 vs 16 uniform b128/thread/step) with ZERO added dot-phase VALU --
// the only mechanism that has ever paid on this step (R0->R1). z-merge is a
// per-thread uint4 write + componentwise sum of 4 uint4 in the gate phase.
#define URQ 24

typedef _Float16 f16;
typedef _Float16 f16x2 __attribute__((ext_vector_type(2)));
typedef _Float16 f16x8 __attribute__((ext_vector_type(8)));
typedef float f32x4 __attribute__((ext_vector_type(4)));

static __device__ __forceinline__ float fdot2(uint32_t h, uint32_t u, float acc) {
#if __has_builtin(__builtin_amdgcn_fdot2)
  return __builtin_amdgcn_fdot2(__builtin_bit_cast(f16x2, h),
                                __builtin_bit_cast(f16x2, u), acc, false);
#else
  f16x2 a = __builtin_bit_cast(f16x2, h);
  f16x2 b = __builtin_bit_cast(f16x2, u);
  return acc + (float)a.x * (float)b.x + (float)a.y * (float)b.y;
#endif
}

// ---------------- K0: pack W_lstm (transposed) and U_lstm (k-pair packed) to f16
__global__ __launch_bounds__(256) void k0_pack(const float* __restrict__ Wl,
                                               const float* __restrict__ Ul,
                                               uint32_t* __restrict__ u_packed,
                                               f16* __restrict__ wt) {
  int idx = blockIdx.x * 256 + threadIdx.x;
  if (idx < 256 * 1024) {              // wt[n][k] = Wl[k][n]
    int n = idx >> 8, k = idx & 255;
    wt[n * 256 + k] = (f16)Wl[k * 1024 + n];
  }
  if (idx < 128 * 1024) {              // u_packed[p][c] = (U[2p][c], U[2p+1][c])
    int p = idx >> 10, c = idx & 1023;
    f16x2 v;
    v.x = (f16)Ul[(2 * p) * 1024 + c];
    v.y = (f16)Ul[(2 * p + 1) * 1024 + c];
    u_packed[idx] = __builtin_bit_cast(uint32_t, v);
  }
}

// ---------------- K1: alpha[b][n] = softmax_n( sum_t X[b,t,n] * Wa[512+t] )
__global__ __launch_bounds__(256) void k1_alpha(const float* __restrict__ X,
                                                const float* __restrict__ Wa,
                                                float* __restrict__ alpha) {
  int b = blockIdx.x, n = threadIdx.x;
  const float* xb = X + b * (T_ * N_) + n;
  float a0 = 0.f, a1 = 0.f, a2 = 0.f, a3 = 0.f;
  int t = 0;
  for (; t + 4 <= T_; t += 4) {
    a0 += xb[(t + 0) * N_] * Wa[512 + t + 0];
    a1 += xb[(t + 1) * N_] * Wa[512 + t + 1];
    a2 += xb[(t + 2) * N_] * Wa[512 + t + 2];
    a3 += xb[(t + 3) * N_] * Wa[512 + t + 3];
  }
  for (; t < T_; ++t) a0 += xb[t * N_] * Wa[512 + t];
  float e = (a0 + a1) + (a2 + a3);

  __shared__ float red[4];
  float m = e;
  for (int off = 32; off > 0; off >>= 1) m = fmaxf(m, __shfl_xor(m, off));
  int wid = n >> 6;
  if ((n & 63) == 0) red[wid] = m;
  __syncthreads();
  m = fmaxf(fmaxf(red[0], red[1]), fmaxf(red[2], red[3]));
  float ex = __expf(e - m);
  float s = ex;
  for (int off = 32; off > 0; off >>= 1) s += __shfl_xor(s, off);
  __syncthreads();
  if ((n & 63) == 0) red[wid] = s;
  __syncthreads();
  s = (red[0] + red[1]) + (red[2] + red[3]);
  alpha[b * N_ + n] = ex / s;
}

// ---------------- K2: X_tilde = alpha (broadcast over t) * X   (exact fp32)
__global__ __launch_bounds__(256) void k2_xtilde(const float4* __restrict__ X4,
                                                 const float* __restrict__ alpha,
                                                 float4* __restrict__ out4) {
  int i = blockIdx.x * 256 + threadIdx.x;  // over B*T*64 float4s
  if (i < B_ * T_ * 64) {
    int n4 = i & 63;
    int bt = i >> 6;
    int b = bt / T_;
    const float4* A4 = (const float4*)alpha;
    float4 x = X4[i], al = A4[b * 64 + n4];
    float4 r;
    r.x = x.x * al.x; r.y = x.y * al.y; r.z = x.z * al.z; r.w = x.w * al.w;
    out4[i] = r;
  }
}

// ---------------- K3: XW = X_tilde @ W_lstm + b_lstm  -> f16 (32640 x 1024)
// UNFUSED (round-1 form, best measured): reads the x_tilde k2 just wrote.
#define LDA 40  // f16 row stride in LDS (16B-aligned rows, bank-spread)
__global__ __launch_bounds__(256, 2) void k3_gemm(const float* __restrict__ A,
                                                  const f16* __restrict__ Bt,
                                                  const float* __restrict__ bias,
                                                  f16* __restrict__ Cw) {
  __shared__ f16 As[128 * LDA];
  __shared__ f16 Bs[128 * LDA];
  int tid = threadIdx.x;
  int mt = blockIdx.x;  // 0..254
  int nt = blockIdx.y;  // 0..7
  int lane = tid & 63, wid = tid >> 6;
  int wm = (wid >> 1) * 64, wn = (wid & 1) * 64;
  f32x4 acc[4][4] = {};

  for (int k0 = 0; k0 < 256; k0 += 32) {
    __syncthreads();
#pragma unroll
    for (int it = 0; it < 4; ++it) {  // A: 128 rows x 32 f32 -> f16
      int idx = tid + it * 256;
      int r = idx >> 3, q = idx & 7;
      float4 v = *(const float4*)(A + (mt * 128 + r) * 256 + k0 + q * 4);
      f16x2 p0, p1;
      p0.x = (f16)v.x; p0.y = (f16)v.y; p1.x = (f16)v.z; p1.y = (f16)v.w;
      uint2 w;
      w.x = __builtin_bit_cast(uint32_t, p0);
      w.y = __builtin_bit_cast(uint32_t, p1);
      *(uint2*)(&As[r * LDA + q * 4]) = w;
    }
#pragma unroll
    for (int it = 0; it < 2; ++it) {  // B (already transposed): 128 rows x 32 f16
      int idx = tid + it * 256;
      int r = idx >> 2, q = idx & 3;
      uint4 v = *(const uint4*)(Bt + (nt * 128 + r) * 256 + k0 + q * 8);
      *(uint4*)(&Bs[r * LDA + q * 8]) = v;
    }
    __syncthreads();
    int kb = (lane >> 4) * 8;
    f16x8 af[4], bf[4];
#pragma unroll
    for (int i = 0; i < 4; ++i)
      af[i] = *(const f16x8*)(&As[(wm + i * 16 + (lane & 15)) * LDA + kb]);
#pragma unroll
    for (int j = 0; j < 4; ++j)
      bf[j] = *(const f16x8*)(&Bs[(wn + j * 16 + (lane & 15)) * LDA + kb]);
#pragma unroll
    for (int i = 0; i < 4; ++i)
#pragma unroll
      for (int j = 0; j < 4; ++j)
        acc[i][j] = __builtin_amdgcn_mfma_f32_16x16x32_f16(af[i], bf[j], acc[i][j], 0, 0, 0);
  }
  int colL = wn + (lane & 15);
  int rowB = wm + (lane >> 4) * 4;
#pragma unroll
  for (int j = 0; j < 4; ++j) {
    int ng = nt * 128 + colL + j * 16;
    float bv = bias[ng];
#pragma unroll
    for (int i = 0; i < 4; ++i)
#pragma unroll
      for (int r = 0; r < 4; ++r) {
        int mg = mt * 128 + rowB + i * 16 + r;
        Cw[mg * 1024 + ng] = (f16)(acc[i][j][r] + bv);
      }
  }
}

// ---------------- K4: sequential LSTM recurrence, one block per batch,
// k-quarter split (see header comment). Per step per thread: 8 uniform h
// b128 reads (chunks kq*8 .. kq*8+7), 128 fdot2 in 4 accumulator chains
// (one per gate of unit n'), 8 per-lane u-LDS uint4 reads interleaved,
// one uint4 z-write. Gate phase (threads 0..255): 4 uint4 z-reads,
// componentwise sum, gates, h + encb write.
__global__ __launch_bounds__(1024) void k4_recur(const float* __restrict__ X,
                                                 const uint32_t* __restrict__ u_packed,
                                                 const f16* __restrict__ xwf,
                                                 float* __restrict__ Xenc) {
  __shared__ __align__(16) uint32_t u_lds[8 * 1024 * 4];  // 128 KB
  __shared__ __align__(16) f16 h_lds[256];                // 512 B
  __shared__ __align__(16) uint4 z4[4 * 256];             // 16 KB [kq][n']
  int tid = threadIdx.x, b = blockIdx.x;
  int kq = tid >> 8, n1 = tid & 255;
  int pb = kq * 32;  // first k-pair of this thread's quarter

  // register U: pairs pb..pb+23 for the 4 gate cols of unit n1
  uint32_t ur[4][URQ];
#pragma unroll
  for (int g = 0; g < 4; ++g)
#pragma unroll
    for (int p = 0; p < URQ; ++p)
      ur[g][p] = u_packed[(pb + p) * 1024 + g * 256 + n1];

  // LDS U: pairs pb+24..pb+31. Plane pl = g*2+j holds, at index tid,
  // the uint4 of pairs (pb+24+4j .. +3) for col g*256+n1.
  {
    uint4* dst = (uint4*)u_lds;
#pragma unroll
    for (int pl = 0; pl < 8; ++pl) {
      int g = pl >> 1, j = pl & 1;
      int bp = pb + URQ + 4 * j;
      uint4 v;
      v.x = u_packed[(bp + 0) * 1024 + g * 256 + n1];
      v.y = u_packed[(bp + 1) * 1024 + g * 256 + n1];
      v.z = u_packed[(bp + 2) * 1024 + g * 256 + n1];
      v.w = u_packed[(bp + 3) * 1024 + g * 256 + n1];
      dst[pl * 1024 + tid] = v;
    }
  }
  float x00 = X[b * (T_ * N_)];
  float c_st = x00;
  if (tid < 256) h_lds[tid] = (f16)x00;
  __syncthreads();

  const f16* xwb = xwf + (size_t)b * T_ * 1024;
  float* encb = Xenc + (size_t)b * T_ * N_;
  const uint4* h4 = (const uint4*)h_lds;  // 16 chunks; this quarter: kq*8..+7
  const uint4* u4 = (const uint4*)u_lds;

  // thread prefetches xw for col tid (= gate kq of unit n1), coalesced
  float xwv = (float)xwb[tid];
  for (int t = 0; t < T_; ++t) {
    float xw_nxt = 0.f;
    if (t + 1 < T_) xw_nxt = (float)xwb[(t + 1) * 1024 + tid];

    // partial z for gate g of unit n1 over this k-quarter; xw lands on g==kq
    float z0 = (kq == 0) ? xwv : 0.f;
    float z1 = (kq == 1) ? xwv : 0.f;
    float z2 = (kq == 2) ? xwv : 0.f;
    float z3 = (kq == 3) ? xwv : 0.f;
#pragma unroll
    for (int j = 0; j < 2; ++j) {
      // issue this sub-iteration's 4 u-LDS reads early (~36 fdot2 of cover)
      uint4 u0 = u4[(0 * 2 + j) * 1024 + tid];
      uint4 u1 = u4[(1 * 2 + j) * 1024 + tid];
      uint4 u2 = u4[(2 * 2 + j) * 1024 + tid];
      uint4 u3 = u4[(3 * 2 + j) * 1024 + tid];
#pragma unroll
      for (int gg = 0; gg < 3; ++gg) {  // register part: chunk c = j*3+gg
        int c = j * 3 + gg;
        uint4 hh = h4[kq * 8 + c];
        z0 = fdot2(hh.x, ur[0][4 * c + 0], z0);
        z1 = fdot2(hh.x, ur[1][4 * c + 0], z1);
        z2 = fdot2(hh.x, ur[2][4 * c + 0], z2);
        z3 = fdot2(hh.x, ur[3][4 * c + 0], z3);
        z0 = fdot2(hh.y, ur[0][4 * c + 1], z0);
        z1 = fdot2(hh.y, ur[1][4 * c + 1], z1);
        z2 = fdot2(hh.y, ur[2][4 * c + 1], z2);
        z3 = fdot2(hh.y, ur[3][4 * c + 1], z3);
        z0 = fdot2(hh.z, ur[0][4 * c + 2], z0);
        z1 = fdot2(hh.z, ur[1][4 * c + 2], z1);
        z2 = fdot2(hh.z, ur[2][4 * c + 2], z2);
        z3 = fdot2(hh.z, ur[3][4 * c + 2], z3);
        z0 = fdot2(hh.w, ur[0][4 * c + 3], z0);
        z1 = fdot2(hh.w, ur[1][4 * c + 3], z1);
        z2 = fdot2(hh.w, ur[2][4 * c + 3], z2);
        z3 = fdot2(hh.w, ur[3][4 * c + 3], z3);
      }
      {  // consume LDS group j: h chunk 6+j (pairs pb+24+4j..+3)
        uint4 hh = h4[kq * 8 + 6 + j];
        z0 = fdot2(hh.x, u0.x, z0);
        z1 = fdot2(hh.x, u1.x, z1);
        z2 = fdot2(hh.x, u2.x, z2);
        z3 = fdot2(hh.x, u3.x, z3);
        z0 = fdot2(hh.y, u0.y, z0);
        z1 = fdot2(hh.y, u1.y, z1);
        z2 = fdot2(hh.y, u2.y, z2);
        z3 = fdot2(hh.y, u3.y, z3);
        z0 = fdot2(hh.z, u0.z, z0);
        z1 = fdot2(hh.z, u1.z, z1);
        z2 = fdot2(hh.z, u2.z, z2);
        z3 = fdot2(hh.z, u3.z, z3);
        z0 = fdot2(hh.w, u0.w, z0);
        z1 = fdot2(hh.w, u1.w, z1);
        z2 = fdot2(hh.w, u2.w, z2);
        z3 = fdot2(hh.w, u3.w, z3);
      }
    }
    {  // one uint4 z-write: {zi,zf,zg,zo} partials for unit n1, quarter kq
      uint4 zw;
      zw.x = __builtin_bit_cast(uint32_t, z0);
      zw.y = __builtin_bit_cast(uint32_t, z1);
      zw.z = __builtin_bit_cast(uint32_t, z2);
      zw.w = __builtin_bit_cast(uint32_t, z3);
      z4[kq * 256 + n1] = zw;
    }
    __syncthreads();
    if (tid < 256) {
      uint4 p0 = z4[tid];
      uint4 p1 = z4[256 + tid];
      uint4 p2 = z4[512 + tid];
      uint4 p3 = z4[768 + tid];
      float zi = (__builtin_bit_cast(float, p0.x) + __builtin_bit_cast(float, p1.x)) +
                 (__builtin_bit_cast(float, p2.x) + __builtin_bit_cast(float, p3.x));
      float zf = (__builtin_bit_cast(float, p0.y) + __builtin_bit_cast(float, p1.y)) +
                 (__builtin_bit_cast(float, p2.y) + __builtin_bit_cast(float, p3.y));
      float zg = (__builtin_bit_cast(float, p0.z) + __builtin_bit_cast(float, p1.z)) +
                 (__builtin_bit_cast(float, p2.z) + __builtin_bit_cast(float, p3.z));
      float zo = (__builtin_bit_cast(float, p0.w) + __builtin_bit_cast(float, p1.w)) +
                 (__builtin_bit_cast(float, p2.w) + __builtin_bit_cast(float, p3.w));
      float ig = 1.f / (1.f + __expf(-zi));
      float fg = 1.f / (1.f + __expf(-zf));
      float gv = 1.f - 2.f / (1.f + __expf(2.f * zg));
      float og = 1.f / (1.f + __expf(-zo));
      c_st = fg * c_st + ig * gv;
      float hv = og * (1.f - 2.f / (1.f + __expf(2.f * c_st)));
      encb[t * 256 + tid] = hv;
      h_lds[tid] = (f16)hv;
    }
    __syncthreads();
    xwv = xw_nxt;
  }
}

extern "C" void kernel_launch(void* const* d_in, const int* in_sizes, int n_in,
                              void* d_out, int out_size, void* d_ws, size_t ws_size,
                              hipStream_t stream) {
  const float* X = (const float*)d_in[0];
  const float* Wa = (const float*)d_in[1];
  const float* Wl = (const float*)d_in[3];
  const float* Ul = (const float*)d_in[4];
  const float* bl = (const float*)d_in[5];
  float* out = (float*)d_out;
  uint8_t* ws = (uint8_t*)d_ws;

  float* alpha = (float*)ws;                          // 131072 B
  uint32_t* u_packed = (uint32_t*)(ws + 131072);      // 524288 B
  f16* wt = (f16*)(ws + 655360);                      // 524288 B
  f16* xw = (f16*)(ws + 1179648);                     // 66846720 B (~68 MB total)

  k0_pack<<<1024, 256, 0, stream>>>(Wl, Ul, u_packed, wt);
  k1_alpha<<<128, 256, 0, stream>>>(X, Wa, alpha);
  k2_xtilde<<<8160, 256, 0, stream>>>((const float4*)X, alpha, (float4*)out);
  dim3 g3(255, 8);
  k3_gemm<<<g3, 256, 0, stream>>>(out, wt, bl, xw);
  k4_recur<<<128, 1024, 0, stream>>>(X, u_packed, xw, out + 8355840);
}

// Round 10
// 539.979 us; speedup vs baseline: 1.1254x; 1.1254x over previous
//
#include <hip/hip_runtime.h>
#include <hip/hip_bf16.h>
#include <stdint.h>

#define B_ 128
#define T_ 255
#define N_ 256
#define H_ 256

// k4 k-split layout (round-1 proven, round-5 tuned, round-8 verified best:
// 486us k4 / 541us total): thread (kh, n2) owns columns n2 and n2+512,
// k-pairs [kh*64, kh*64+64). 48 pairs/col in registers (96 regs), 16
// pairs/col in LDS (8 planes x 1024 cols x uint4 = 128 KB), u-LDS reads
// interleaved into the register-fdot2 loop. Probes that LOST on this step:
// quad/quarter splits (VALU or spill payback: R4 +13%, R9 +14% -- R9's
// +4MB WRITE_SIZE = scratch, live-set crossed the 128-VGPR cap), readlane
// broadcast (R7 +17%), LDS-only barriers (R6 neutral), cross-block
// pipelining (R2, 8x -- per-step L2 handshake is a non-starter).
#define RP2 48
#define LG2 4

typedef _Float16 f16;
typedef _Float16 f16x2 __attribute__((ext_vector_type(2)));
typedef _Float16 f16x8 __attribute__((ext_vector_type(8)));
typedef float f32x4 __attribute__((ext_vector_type(4)));

static __device__ __forceinline__ float fdot2(uint32_t h, uint32_t u, float acc) {
#if __has_builtin(__builtin_amdgcn_fdot2)
  return __builtin_amdgcn_fdot2(__builtin_bit_cast(f16x2, h),
                                __builtin_bit_cast(f16x2, u), acc, false);
#else
  f16x2 a = __builtin_bit_cast(f16x2, h);
  f16x2 b = __builtin_bit_cast(f16x2, u);
  return acc + (float)a.x * (float)b.x + (float)a.y * (float)b.y;
#endif
}

// ---------------- K0: pack W_lstm (transposed) and U_lstm (k-pair packed) to f16
__global__ __launch_bounds__(256) void k0_pack(const float* __restrict__ Wl,
                                               const float* __restrict__ Ul,
                                               uint32_t* __restrict__ u_packed,
                                               f16* __restrict__ wt) {
  int idx = blockIdx.x * 256 + threadIdx.x;
  if (idx < 256 * 1024) {              // wt[n][k] = Wl[k][n]
    int n = idx >> 8, k = idx & 255;
    wt[n * 256 + k] = (f16)Wl[k * 1024 + n];
  }
  if (idx < 128 * 1024) {              // u_packed[p][c] = (U[2p][c], U[2p+1][c])
    int p = idx >> 10, c = idx & 1023;
    f16x2 v;
    v.x = (f16)Ul[(2 * p) * 1024 + c];
    v.y = (f16)Ul[(2 * p + 1) * 1024 + c];
    u_packed[idx] = __builtin_bit_cast(uint32_t, v);
  }
}

// ---------------- K1: alpha[b][n] = softmax_n( sum_t X[b,t,n] * Wa[512+t] )
__global__ __launch_bounds__(256) void k1_alpha(const float* __restrict__ X,
                                                const float* __restrict__ Wa,
                                                float* __restrict__ alpha) {
  int b = blockIdx.x, n = threadIdx.x;
  const float* xb = X + b * (T_ * N_) + n;
  float a0 = 0.f, a1 = 0.f, a2 = 0.f, a3 = 0.f;
  int t = 0;
  for (; t + 4 <= T_; t += 4) {
    a0 += xb[(t + 0) * N_] * Wa[512 + t + 0];
    a1 += xb[(t + 1) * N_] * Wa[512 + t + 1];
    a2 += xb[(t + 2) * N_] * Wa[512 + t + 2];
    a3 += xb[(t + 3) * N_] * Wa[512 + t + 3];
  }
  for (; t < T_; ++t) a0 += xb[t * N_] * Wa[512 + t];
  float e = (a0 + a1) + (a2 + a3);

  __shared__ float red[4];
  float m = e;
  for (int off = 32; off > 0; off >>= 1) m = fmaxf(m, __shfl_xor(m, off));
  int wid = n >> 6;
  if ((n & 63) == 0) red[wid] = m;
  __syncthreads();
  m = fmaxf(fmaxf(red[0], red[1]), fmaxf(red[2], red[3]));
  float ex = __expf(e - m);
  float s = ex;
  for (int off = 32; off > 0; off >>= 1) s += __shfl_xor(s, off);
  __syncthreads();
  if ((n & 63) == 0) red[wid] = s;
  __syncthreads();
  s = (red[0] + red[1]) + (red[2] + red[3]);
  alpha[b * N_ + n] = ex / s;
}

// ---------------- K2: X_tilde = alpha (broadcast over t) * X   (exact fp32)
__global__ __launch_bounds__(256) void k2_xtilde(const float4* __restrict__ X4,
                                                 const float* __restrict__ alpha,
                                                 float4* __restrict__ out4) {
  int i = blockIdx.x * 256 + threadIdx.x;  // over B*T*64 float4s
  if (i < B_ * T_ * 64) {
    int n4 = i & 63;
    int bt = i >> 6;
    int b = bt / T_;
    const float4* A4 = (const float4*)alpha;
    float4 x = X4[i], al = A4[b * 64 + n4];
    float4 r;
    r.x = x.x * al.x; r.y = x.y * al.y; r.z = x.z * al.z; r.w = x.w * al.w;
    out4[i] = r;
  }
}

// ---------------- K3: XW = X_tilde @ W_lstm + b_lstm  -> f16 (32640 x 1024)
// UNFUSED (round-1 form, best measured): reads the x_tilde k2 just wrote
// (L2/L3-hot). The alpha-fused variant cost ~9us extra in the staging loop.
#define LDA 40  // f16 row stride in LDS (16B-aligned rows, bank-spread)
__global__ __launch_bounds__(256, 2) void k3_gemm(const float* __restrict__ A,
                                                  const f16* __restrict__ Bt,
                                                  const float* __restrict__ bias,
                                                  f16* __restrict__ Cw) {
  __shared__ f16 As[128 * LDA];
  __shared__ f16 Bs[128 * LDA];
  int tid = threadIdx.x;
  int mt = blockIdx.x;  // 0..254
  int nt = blockIdx.y;  // 0..7
  int lane = tid & 63, wid = tid >> 6;
  int wm = (wid >> 1) * 64, wn = (wid & 1) * 64;
  f32x4 acc[4][4] = {};

  for (int k0 = 0; k0 < 256; k0 += 32) {
    __syncthreads();
#pragma unroll
    for (int it = 0; it < 4; ++it) {  // A: 128 rows x 32 f32 -> f16
      int idx = tid + it * 256;
      int r = idx >> 3, q = idx & 7;
      float4 v = *(const float4*)(A + (mt * 128 + r) * 256 + k0 + q * 4);
      f16x2 p0, p1;
      p0.x = (f16)v.x; p0.y = (f16)v.y; p1.x = (f16)v.z; p1.y = (f16)v.w;
      uint2 w;
      w.x = __builtin_bit_cast(uint32_t, p0);
      w.y = __builtin_bit_cast(uint32_t, p1);
      *(uint2*)(&As[r * LDA + q * 4]) = w;
    }
#pragma unroll
    for (int it = 0; it < 2; ++it) {  // B (already transposed): 128 rows x 32 f16
      int idx = tid + it * 256;
      int r = idx >> 2, q = idx & 3;
      uint4 v = *(const uint4*)(Bt + (nt * 128 + r) * 256 + k0 + q * 8);
      *(uint4*)(&Bs[r * LDA + q * 8]) = v;
    }
    __syncthreads();
    int kb = (lane >> 4) * 8;
    f16x8 af[4], bf[4];
#pragma unroll
    for (int i = 0; i < 4; ++i)
      af[i] = *(const f16x8*)(&As[(wm + i * 16 + (lane & 15)) * LDA + kb]);
#pragma unroll
    for (int j = 0; j < 4; ++j)
      bf[j] = *(const f16x8*)(&Bs[(wn + j * 16 + (lane & 15)) * LDA + kb]);
#pragma unroll
    for (int i = 0; i < 4; ++i)
#pragma unroll
      for (int j = 0; j < 4; ++j)
        acc[i][j] = __builtin_amdgcn_mfma_f32_16x16x32_f16(af[i], bf[j], acc[i][j], 0, 0, 0);
  }
  int colL = wn + (lane & 15);
  int rowB = wm + (lane >> 4) * 4;
#pragma unroll
  for (int j = 0; j < 4; ++j) {
    int ng = nt * 128 + colL + j * 16;
    float bv = bias[ng];
#pragma unroll
    for (int i = 0; i < 4; ++i)
#pragma unroll
      for (int r = 0; r < 4; ++r) {
        int mg = mt * 128 + rowB + i * 16 + r;
        Cw[mg * 1024 + ng] = (f16)(acc[i][j][r] + bv);
      }
  }
}

// ---------------- K4: sequential LSTM recurrence, one block per batch.
// Round-5 version verbatim (best measured: 486us).
__global__ __launch_bounds__(1024) void k4_recur(const float* __restrict__ X,
                                                 const uint32_t* __restrict__ u_packed,
                                                 const f16* __restrict__ xwf,
                                                 float* __restrict__ Xenc) {
  __shared__ __align__(16) uint32_t u_lds[8 * 1024 * 4];  // 128 KB
  __shared__ __align__(16) f16 h_lds[256];                // 512 B
  __shared__ __align__(16) float z_lds[2048];             // 8 KB ([kh][col])
  int tid = threadIdx.x, b = blockIdx.x;
  int kh = tid >> 9, n2 = tid & 511;

  // register part: pairs [kh*64, kh*64+RP2) for cols n2 and n2+512
  uint32_t urA[RP2], urB[RP2];
  int pbase = kh * 64;
#pragma unroll
  for (int p = 0; p < RP2; ++p) {
    urA[p] = u_packed[(pbase + p) * 1024 + n2];
    urB[p] = u_packed[(pbase + p) * 1024 + n2 + 512];
  }
  // LDS part: plane pl = g*2 + kh2 holds pairs (kh2*64 + RP2 + 4g .. +3)
  // for all 1024 cols, uint4-interleaved.
  {
    uint4* dst = (uint4*)u_lds;
#pragma unroll
    for (int pl = 0; pl < 2 * LG2; ++pl) {
      int kh2 = pl & 1, g = pl >> 1;
      int bp = kh2 * 64 + RP2 + 4 * g;
      uint4 v;
      v.x = u_packed[(bp + 0) * 1024 + tid];
      v.y = u_packed[(bp + 1) * 1024 + tid];
      v.z = u_packed[(bp + 2) * 1024 + tid];
      v.w = u_packed[(bp + 3) * 1024 + tid];
      dst[pl * 1024 + tid] = v;
    }
  }
  float x00 = X[b * (T_ * N_)];
  float c_st = x00;
  if (tid < 256) h_lds[tid] = (f16)x00;
  __syncthreads();

  const f16* xwb = xwf + (size_t)b * T_ * 1024;
  float* encb = Xenc + (size_t)b * T_ * N_;
  const uint4* h4 = (const uint4*)h_lds;
  const uint4* u4 = (const uint4*)u_lds;

  // each thread prefetches xw for its "own" column (== tid), coalesced
  float xwv = (float)xwb[tid];
  for (int t = 0; t < T_; ++t) {
    float xw_nxt = 0.f;
    if (t + 1 < T_) xw_nxt = (float)xwb[(t + 1) * 1024 + tid];

    float zA0 = (kh == 0) ? xwv : 0.f, zA1 = 0.f;  // col n2
    float zB0 = (kh == 0) ? 0.f : xwv, zB1 = 0.f;  // col n2+512
#pragma unroll
    for (int j = 0; j < LG2; ++j) {
      // issue this sub-iteration's u-LDS loads early; ~24 fdot2 of cover
      uint4 uA = u4[(j * 2 + kh) * 1024 + n2];
      uint4 uB = u4[(j * 2 + kh) * 1024 + n2 + 512];
#pragma unroll
      for (int gg = 0; gg < 3; ++gg) {  // register part: pairs 4g..4g+3
        int g = j * 3 + gg;
        uint4 hh = h4[kh * 16 + g];
        zA0 = fdot2(hh.x, urA[4 * g + 0], zA0);
        zA1 = fdot2(hh.y, urA[4 * g + 1], zA1);
        zA0 = fdot2(hh.z, urA[4 * g + 2], zA0);
        zA1 = fdot2(hh.w, urA[4 * g + 3], zA1);
        zB0 = fdot2(hh.x, urB[4 * g + 0], zB0);
        zB1 = fdot2(hh.y, urB[4 * g + 1], zB1);
        zB0 = fdot2(hh.z, urB[4 * g + 2], zB0);
        zB1 = fdot2(hh.w, urB[4 * g + 3], zB1);
      }
      {  // consume LDS group j (h pairs RP2+4j .. +3)
        uint4 hh = h4[kh * 16 + RP2 / 4 + j];
        zA0 = fdot2(hh.x, uA.x, zA0);
        zA1 = fdot2(hh.y, uA.y, zA1);
        zA0 = fdot2(hh.z, uA.z, zA0);
        zA1 = fdot2(hh.w, uA.w, zA1);
        zB0 = fdot2(hh.x, uB.x, zB0);
        zB1 = fdot2(hh.y, uB.y, zB1);
        zB0 = fdot2(hh.z, uB.z, zB0);
        zB1 = fdot2(hh.w, uB.w, zB1);
      }
    }
    z_lds[kh * 1024 + n2] = zA0 + zA1;
    z_lds[kh * 1024 + n2 + 512] = zB0 + zB1;
    __syncthreads();
    if (tid < 256) {
      float zi = z_lds[tid] + z_lds[1024 + tid];
      float zf = z_lds[256 + tid] + z_lds[1280 + tid];
      float zg = z_lds[512 + tid] + z_lds[1536 + tid];
      float zo = z_lds[768 + tid] + z_lds[1792 + tid];
      float ig = 1.f / (1.f + __expf(-zi));
      float fg = 1.f / (1.f + __expf(-zf));
      float gg = 1.f - 2.f / (1.f + __expf(2.f * zg));
      float og = 1.f / (1.f + __expf(-zo));
      c_st = fg * c_st + ig * gg;
      float hv = og * (1.f - 2.f / (1.f + __expf(2.f * c_st)));
      encb[t * 256 + tid] = hv;
      h_lds[tid] = (f16)hv;
    }
    __syncthreads();
    xwv = xw_nxt;
  }
}

extern "C" void kernel_launch(void* const* d_in, const int* in_sizes, int n_in,
                              void* d_out, int out_size, void* d_ws, size_t ws_size,
                              hipStream_t stream) {
  const float* X = (const float*)d_in[0];
  const float* Wa = (const float*)d_in[1];
  const float* Wl = (const float*)d_in[3];
  const float* Ul = (const float*)d_in[4];
  const float* bl = (const float*)d_in[5];
  float* out = (float*)d_out;
  uint8_t* ws = (uint8_t*)d_ws;

  float* alpha = (float*)ws;                          // 131072 B
  uint32_t* u_packed = (uint32_t*)(ws + 131072);      // 524288 B
  f16* wt = (f16*)(ws + 655360);                      // 524288 B
  f16* xw = (f16*)(ws + 1179648);                     // 66846720 B (~68 MB total)

  k0_pack<<<1024, 256, 0, stream>>>(Wl, Ul, u_packed, wt);
  k1_alpha<<<128, 256, 0, stream>>>(X, Wa, alpha);
  k2_xtilde<<<8160, 256, 0, stream>>>((const float4*)X, alpha, (float4*)out);
  dim3 g3(255, 8);
  k3_gemm<<<g3, 256, 0, stream>>>(out, wt, bl, xw);
  k4_recur<<<128, 1024, 0, stream>>>(X, u_packed, xw, out + 8355840);
}